// Round 3
// baseline (249.717 us; speedup 1.0000x reference)
//
#include <hip/hip_runtime.h>
#include <math.h>

#define NB   512            // histogram bins over (0,1)
#define CAP  1024           // boundary-bin collection capacity per row
#define SEG  8192           // elements per segment block
#define BLK  256

__device__ __forceinline__ int bin_of(float x) {
    int b = (int)(x * (float)NB);
    return b > NB - 1 ? NB - 1 : b;
}

// ---- phase 0: zero the workspace pieces we accumulate into ----
__global__ void zero_kernel(int* __restrict__ ghist, float* __restrict__ rowsum,
                            int* __restrict__ bufcnt, float* __restrict__ out,
                            int nh, int B) {
    const int i = blockIdx.x * blockDim.x + threadIdx.x;
    if (i < nh) ghist[i] = 0;
    if (i < B) { rowsum[i] = 0.f; bufcnt[i] = 0; }
    if (i == 0) out[0] = 0.f;
}

// ---- phase 1: segmented histogram (LDS -> global per-row, atomics) ----
__global__ __launch_bounds__(BLK) void hist_kernel(
    const float* __restrict__ scores, const int* __restrict__ seqlen,
    int* __restrict__ ghist, int T, int nseg)
{
    const int gid = blockIdx.x;
    const int row = gid / nseg;
    const int seg = gid - row * nseg;
    const int n   = seqlen[row];
    const int s0  = seg * SEG;
    int cn = n - s0;
    if (cn <= 0) return;               // block-uniform exit
    if (cn > SEG) cn = SEG;

    __shared__ int h[NB];              // 2 KB
    for (int i = threadIdx.x; i < NB; i += BLK) h[i] = 0;
    __syncthreads();

    const float*  rp  = scores + (size_t)row * (size_t)T + s0;
    const float4* rp4 = (const float4*)rp;   // s0 multiple of SEG -> 16B aligned
    const int n4 = cn >> 2;
    for (int j = threadIdx.x; j < n4; j += BLK) {
        float4 v = rp4[j];
        atomicAdd(&h[bin_of(v.x)], 1);
        atomicAdd(&h[bin_of(v.y)], 1);
        atomicAdd(&h[bin_of(v.z)], 1);
        atomicAdd(&h[bin_of(v.w)], 1);
    }
    for (int j = (n4 << 2) + threadIdx.x; j < cn; j += BLK)
        atomicAdd(&h[bin_of(rp[j])], 1);
    __syncthreads();

    int* gh = ghist + (size_t)row * NB;
    for (int i = threadIdx.x; i < NB; i += BLK) {
        const int c = h[i];
        if (c) atomicAdd(&gh[i], c);   // ~63% of bins nonzero
    }
}

// ---- phase 2: per-row boundary-bin select (b, r) via suffix scan ----
__global__ __launch_bounds__(BLK) void select_kernel(
    const int* __restrict__ ghist, const int* __restrict__ seqlen,
    int2* __restrict__ brs)
{
    __shared__ int c[NB];
    __shared__ int schunk[BLK];
    __shared__ int s_t, s_above;

    const int row = blockIdx.x;
    const int tid = threadIdx.x;
    const int n   = seqlen[row];
    const int k   = (n >> 4) + 1;      // k <= n always
    const int* gh = ghist + (size_t)row * NB;

    for (int i = tid; i < NB; i += BLK) c[i] = gh[i];
    __syncthreads();

    schunk[tid] = c[2 * tid] + c[2 * tid + 1];
    __syncthreads();
    // inclusive suffix scan over 256 chunks (Hillis-Steele)
    for (int off = 1; off < BLK; off <<= 1) {
        int v = schunk[tid];
        if (tid + off < BLK) v += schunk[tid + off];
        __syncthreads();
        schunk[tid] = v;
        __syncthreads();
    }
    {
        const int SA  = schunk[tid];
        const int SAn = (tid + 1 < BLK) ? schunk[tid + 1] : 0;
        if (SA >= k && SAn < k) { s_t = tid; s_above = SAn; } // unique thread
    }
    __syncthreads();

    if (tid == 0) {
        const int t     = s_t;
        const int above = s_above;     // count in bins [2t+2, NB)
        int b, r;
        const int c_hi = c[2 * t + 1];
        if (above + c_hi >= k) { b = 2 * t + 1; r = k - above; }
        else                   { b = 2 * t;     r = k - above - c_hi; }
        brs[row] = make_int2(b, r);    // 1 <= r <= cnt[b] guaranteed
    }
}

// ---- phase 3: segmented sum of bins > b; collect bin-b values exactly ----
__global__ __launch_bounds__(BLK) void collect_kernel(
    const float* __restrict__ scores, const int* __restrict__ seqlen,
    const int2* __restrict__ brs, float* __restrict__ rowsum,
    int* __restrict__ bufcnt, float* __restrict__ bbuf, int T, int nseg)
{
    const int gid = blockIdx.x;
    const int row = gid / nseg;
    const int seg = gid - row * nseg;
    const int n   = seqlen[row];
    const int s0  = seg * SEG;
    int cn = n - s0;
    if (cn <= 0) return;
    if (cn > SEG) cn = SEG;

    const int b = brs[row].x;
    const float*  rp  = scores + (size_t)row * (size_t)T + s0;
    const float4* rp4 = (const float4*)rp;
    float* bb = bbuf + (size_t)row * CAP;
    int*   bc = bufcnt + row;

    float lsum = 0.f;
#define PROC(x) do { \
        const float _x = (x); \
        const int _bn = bin_of(_x); \
        if (_bn > b) lsum += _x; \
        else if (_bn == b) { \
            int p = atomicAdd(bc, 1); \
            if (p < CAP) bb[p] = _x; \
        } \
    } while (0)

    const int n4 = cn >> 2;
    for (int j = threadIdx.x; j < n4; j += BLK) {
        float4 v = rp4[j];
        PROC(v.x); PROC(v.y); PROC(v.z); PROC(v.w);
    }
    for (int j = (n4 << 2) + threadIdx.x; j < cn; j += BLK) PROC(rp[j]);
#undef PROC

    // block-reduce lsum -> one global atomic per block
    __shared__ float wsum[BLK / 64];
    for (int off = 32; off > 0; off >>= 1) lsum += __shfl_down(lsum, off, 64);
    if ((threadIdx.x & 63) == 0) wsum[threadIdx.x >> 6] = lsum;
    __syncthreads();
    if (threadIdx.x == 0)
        atomicAdd(&rowsum[row], wsum[0] + wsum[1] + wsum[2] + wsum[3]);
}

// ---- phase 4: per-row wave-parallel top-r selection + BCE + reduce ----
__global__ __launch_bounds__(64) void final_kernel(
    const float* __restrict__ label, const int* __restrict__ seqlen,
    const int2* __restrict__ brs, const float* __restrict__ rowsum,
    const int* __restrict__ bufcnt, const float* __restrict__ bbuf,
    float* __restrict__ out, int B)
{
    const int row  = blockIdx.x;
    const int lane = threadIdx.x;
    const int n    = seqlen[row];
    const int k    = (n >> 4) + 1;
    const int2 br  = brs[row];
    const int r0   = br.y;
    int m = bufcnt[row]; if (m > CAP) m = CAP;
    const int rr = r0 < m ? r0 : m;    // == r0 unless pathological overflow
    const float* bb = bbuf + (size_t)row * CAP;

    float local[CAP / 64];             // 16 regs, constant-bound loops only
    #pragma unroll
    for (int j = 0; j < CAP / 64; ++j) {
        const int idx = lane + 64 * j;
        local[j] = (idx < m) ? bb[idx] : -1.f;
    }

    float tot = 0.f;
    for (int s = 0; s < rr; ++s) {
        float lm = -1.f; int li = 0;
        #pragma unroll
        for (int j = 0; j < CAP / 64; ++j)
            if (local[j] > lm) { lm = local[j]; li = j; }
        float wm = lm;
        #pragma unroll
        for (int off = 32; off > 0; off >>= 1)
            wm = fmaxf(wm, __shfl_down(wm, off, 64));
        wm = __shfl(wm, 0, 64);
        const unsigned long long ball = __ballot(lm == wm);
        const int owner = (int)__ffsll(ball) - 1;  // remove exactly one instance
        if (lane == owner) {
            #pragma unroll
            for (int j = 0; j < CAP / 64; ++j)
                if (j == li) local[j] = -1.f;
        }
        tot += wm;
    }

    if (lane == 0) {
        float top = tot;
        if (r0 > rr)  // overflow fallback, bounded error, never hit for uniform data
            top += (float)(r0 - rr) * (((float)br.x + 0.5f) / (float)NB);
        float v = (rowsum[row] + top) / (float)k;
        v = fminf(fmaxf(v, 1e-12f), 1.f - 1e-7f);
        const float lab  = label[row];
        const float loss = -(lab * logf(v) + (1.f - lab) * log1pf(-v));
        atomicAdd(out, loss / (float)B);   // device-scope, cross-XCD safe
    }
}

extern "C" void kernel_launch(void* const* d_in, const int* in_sizes, int n_in,
                              void* d_out, int out_size, void* d_ws, size_t ws_size,
                              hipStream_t stream) {
    const float* scores = (const float*)d_in[0];
    const float* label  = (const float*)d_in[1];
    const int*   seqlen = (const int*)d_in[2];
    float* out = (float*)d_out;

    const int B = in_sizes[1];
    const int T = in_sizes[0] / B;
    const int nseg = (T + SEG - 1) / SEG;

    // workspace layout (all offsets 8B-aligned)
    char* ws = (char*)d_ws;
    int*   ghist  = (int*)ws;                                        // B*NB ints (2 MB)
    float* rowsum = (float*)(ws + (size_t)B * NB * 4);               // B floats
    int*   bufcnt = (int*)  (ws + (size_t)B * NB * 4 + (size_t)B * 4);
    int2*  brs    = (int2*) (ws + (size_t)B * NB * 4 + (size_t)B * 8);
    float* bbuf   = (float*)(ws + (size_t)B * NB * 4 + (size_t)B * 16); // B*CAP floats (4 MB)

    const int nh = B * NB;
    const int zmax = nh > B ? nh : B;
    zero_kernel<<<(zmax + 255) / 256, 256, 0, stream>>>(ghist, rowsum, bufcnt, out, nh, B);
    hist_kernel<<<B * nseg, BLK, 0, stream>>>(scores, seqlen, ghist, T, nseg);
    select_kernel<<<B, BLK, 0, stream>>>(ghist, seqlen, brs);
    collect_kernel<<<B * nseg, BLK, 0, stream>>>(scores, seqlen, brs, rowsum, bufcnt, bbuf, T, nseg);
    final_kernel<<<B, 64, 0, stream>>>(label, seqlen, brs, rowsum, bufcnt, bbuf, out, B);
}

// Round 4
// 190.578 us; speedup vs baseline: 1.3103x; 1.3103x over previous
//
#include <hip/hip_runtime.h>
#include <math.h>

#define NB    2048           // histogram bins over (0,1)
#define BLK   256            // threads per block
#define CHW   (NB / BLK)     // 8 bins per scan chunk
#define FIXS  1048576.0f     // 2^20 fixed-point scale for value sums
#define SUMMASK ((1ULL << 44) - 1)

// Packed bin entry: (count << 44) | fixed20_sum.
// count <= 32768 < 2^20; sum < 32768 * 2^20 = 2^35 < 2^44. No overflow.

__global__ void zero_out_kernel(float* __restrict__ out) { out[0] = 0.0f; }

__global__ __launch_bounds__(BLK) void topk_bce_kernel(
    const float* __restrict__ scores,
    const float* __restrict__ label,
    const int*   __restrict__ seqlen,
    float*       __restrict__ out,
    int T, int B)
{
    __shared__ unsigned long long hist[NB];     // 16 KB
    __shared__ int                sc_cnt[BLK];  // 1 KB
    __shared__ unsigned long long sc_sum[BLK];  // 2 KB
    __shared__ int s_t, s_acc;
    __shared__ unsigned long long s_vs;

    const int row = blockIdx.x;
    const int tid = threadIdx.x;
    const int n   = seqlen[row];               // 1..T
    const int k   = (n >> 4) + 1;              // k = n/16 + 1, k <= n always
    const float* rp   = scores + (size_t)row * (size_t)T;
    const float4* rp4 = (const float4*)rp;     // row base 128KB-aligned
    const int n4 = n >> 2;

    // ---- init ----
    for (int i = tid; i < NB; i += BLK) hist[i] = 0ULL;
    __syncthreads();

    // ---- single pass: packed count+sum histogram ----
#define PUT(x) do { \
        const float _x = (x); \
        int _b = (int)(_x * (float)NB); \
        if (_b > NB - 1) _b = NB - 1; \
        const unsigned int _q = (unsigned int)(_x * FIXS + 0.5f); \
        atomicAdd(&hist[_b], (1ULL << 44) | (unsigned long long)_q); \
    } while (0)

    for (int j = tid; j < n4; j += BLK) {
        float4 v = rp4[j];
        PUT(v.x); PUT(v.y); PUT(v.z); PUT(v.w);
    }
    for (int j = (n4 << 2) + tid; j < n; j += BLK) PUT(rp[j]);
#undef PUT
    __syncthreads();

    // ---- per-thread chunk totals (8 bins each) ----
    {
        int cc = 0; unsigned long long ss = 0ULL;
        const int base = tid * CHW;
        #pragma unroll
        for (int j = 0; j < CHW; ++j) {
            const unsigned long long h = hist[base + j];
            cc += (int)(h >> 44);
            ss += (h & SUMMASK);
        }
        sc_cnt[tid] = cc; sc_sum[tid] = ss;
    }
    __syncthreads();

    // ---- inclusive suffix scan over 256 chunks (counts + sums together) ----
    for (int off = 1; off < BLK; off <<= 1) {
        int vc = sc_cnt[tid];
        unsigned long long vs = sc_sum[tid];
        if (tid + off < BLK) { vc += sc_cnt[tid + off]; vs += sc_sum[tid + off]; }
        __syncthreads();
        sc_cnt[tid] = vc; sc_sum[tid] = vs;
        __syncthreads();
    }

    // ---- locate boundary chunk: S[t] >= k > S[t+1]; unique t ----
    {
        const int SA  = sc_cnt[tid];
        const int SAn = (tid + 1 < BLK) ? sc_cnt[tid + 1] : 0;
        if (SA >= k && SAn < k) {
            s_t   = tid;
            s_acc = SAn;                                   // count in bins > chunk
            s_vs  = (tid + 1 < BLK) ? sc_sum[tid + 1] : 0ULL; // sum in bins > chunk
        }
    }
    __syncthreads();

    // ---- thread 0: walk <=8 bins, compute loss, accumulate ----
    if (tid == 0) {
        const int t = s_t;
        int acc = s_acc;                 // count of elements strictly above current bin
        unsigned long long vs = s_vs;    // fixed-point sum of those elements
        for (int j = CHW - 1; j >= 0; --j) {
            const int bin = t * CHW + j;
            const unsigned long long h = hist[bin];
            const int c = (int)(h >> 44);
            if (acc + c >= k) {
                const int r = k - acc;   // 1 <= r <= c
                const int m = c;
                const float sum_b = (float)(h & SUMMASK) * (1.0f / FIXS);
                const float above = (float)vs * (1.0f / FIXS);
                const float binw  = 1.0f / (float)NB;
                const float lo    = (float)bin * binw;
                float topr;
                if (r >= m) {
                    topr = sum_b;        // whole bin selected: EXACT
                } else if (2 * r <= m) {
                    // top-r of m uniforms in [lo, lo+binw): order-stat estimate
                    topr = (float)r * (lo + binw)
                         - binw * (float)r * (float)(r + 1) / (2.0f * (float)(m + 1));
                } else {
                    // complement: exact bin sum minus bottom (m-r) estimate
                    const int q2 = m - r;
                    topr = sum_b - ((float)q2 * lo
                         + binw * (float)q2 * (float)(q2 + 1) / (2.0f * (float)(m + 1)));
                }
                float v = (above + topr) / (float)k;
                v = fminf(fmaxf(v, 1e-9f), 1.0f - 1e-7f);
                const float lab  = label[row];
                const float loss = -(lab * logf(v) + (1.0f - lab) * log1pf(-v));
                atomicAdd(out, loss / (float)B);   // device-scope, cross-XCD safe
                break;
            }
            acc += c;
            vs  += (h & SUMMASK);
        }
    }
}

extern "C" void kernel_launch(void* const* d_in, const int* in_sizes, int n_in,
                              void* d_out, int out_size, void* d_ws, size_t ws_size,
                              hipStream_t stream) {
    const float* scores = (const float*)d_in[0];
    const float* label  = (const float*)d_in[1];
    const int*   seqlen = (const int*)d_in[2];
    float* out = (float*)d_out;

    const int B = in_sizes[1];
    const int T = in_sizes[0] / B;

    // d_out re-poisoned (0xAA) before every timed launch: zero via kernel
    // (no runtime API calls inside kernel_launch -> graph-capture safe).
    zero_out_kernel<<<1, 1, 0, stream>>>(out);
    topk_bce_kernel<<<B, BLK, 0, stream>>>(scores, label, seqlen, out, T, B);
}

// Round 5
// 184.149 us; speedup vs baseline: 1.3561x; 1.0349x over previous
//
#include <hip/hip_runtime.h>
#include <math.h>

#define NB    2048           // histogram bins
#define BLK   1024           // threads per block (16 waves)
#define NCH   256            // scan chunks
#define CHW   (NB / NCH)     // 8 bins per chunk
#define FIXS  1048576.0f     // 2^20 fixed-point scale for value sums
#define SUMMASK ((1ULL << 44) - 1)

// Packed bin entry: (count << 44) | fixed20_sum_of_raw_x.
// count <= 32768 < 2^20; sum < 32768 * 2^20 = 2^35 < 2^44. No overflow.
//
// Fast path: only values >= 7/8 are binned (expected 12.5% of elements,
// ~2x the k/n = 1/16 selection rate -> boundary is binned whp). Bin width
// (1/8)/2048 = 6.1e-5. Block-uniform fallback to full-range [0,1) mapping
// (identical to the previous, validated kernel) when binned total < k.

__global__ void zero_out_kernel(float* __restrict__ out) { out[0] = 0.0f; }

__global__ __launch_bounds__(BLK) void topk_bce_kernel(
    const float* __restrict__ scores,
    const float* __restrict__ label,
    const int*   __restrict__ seqlen,
    float*       __restrict__ out,
    int T, int B)
{
    __shared__ unsigned long long hist[NB];     // 16 KB
    __shared__ int                sc_cnt[NCH];  // 1 KB
    __shared__ unsigned long long sc_sum[NCH];  // 2 KB
    __shared__ int s_t, s_acc;
    __shared__ unsigned long long s_vs;

    const int row = blockIdx.x;
    const int tid = threadIdx.x;
    const int n   = seqlen[row];               // 1..T
    const int k   = (n >> 4) + 1;              // k = n/16 + 1, k <= n always
    const float* rp   = scores + (size_t)row * (size_t)T;
    const float4* rp4 = (const float4*)rp;     // row base 128KB-aligned
    const int n4 = n >> 2;

    float lo  = 0.875f;                        // 7/8, exact
    float mul = 16384.0f;                      // NB / (1 - 7/8), exact

    for (;;) {
        // ---- zero histogram ----
        for (int i = tid; i < NB; i += BLK) hist[i] = 0ULL;
        __syncthreads();

        // ---- pass: bin only values >= lo ----
#define PUT(x) do { \
            const float _x = (x); \
            if (_x >= lo) { \
                int _b = (int)((_x - lo) * mul); \
                if (_b > NB - 1) _b = NB - 1; \
                const unsigned int _q = (unsigned int)(_x * FIXS + 0.5f); \
                atomicAdd(&hist[_b], (1ULL << 44) | (unsigned long long)_q); \
            } \
        } while (0)

        for (int j = tid; j < n4; j += BLK) {
            float4 v = rp4[j];
            PUT(v.x); PUT(v.y); PUT(v.z); PUT(v.w);
        }
        for (int j = (n4 << 2) + tid; j < n; j += BLK) PUT(rp[j]);
#undef PUT
        __syncthreads();

        // ---- per-chunk totals (threads 0..255, 8 bins each) ----
        if (tid < NCH) {
            int cc = 0; unsigned long long ss = 0ULL;
            const int base = tid * CHW;
            #pragma unroll
            for (int j = 0; j < CHW; ++j) {
                const unsigned long long h = hist[base + j];
                cc += (int)(h >> 44);
                ss += (h & SUMMASK);
            }
            sc_cnt[tid] = cc; sc_sum[tid] = ss;
        }
        __syncthreads();

        // ---- inclusive suffix scan over 256 chunks ----
        for (int off = 1; off < NCH; off <<= 1) {
            int vc = 0; unsigned long long vs = 0ULL;
            if (tid < NCH) {
                vc = sc_cnt[tid]; vs = sc_sum[tid];
                if (tid + off < NCH) { vc += sc_cnt[tid + off]; vs += sc_sum[tid + off]; }
            }
            __syncthreads();
            if (tid < NCH) { sc_cnt[tid] = vc; sc_sum[tid] = vs; }
            __syncthreads();
        }

        const int total = sc_cnt[0];           // binned count (block-uniform read)
        if (total >= k) break;                 // boundary is inside binned region
        // fallback: full-range mapping (total becomes n >= k, always succeeds)
        lo = 0.0f; mul = (float)NB;
    }

    // ---- locate boundary chunk: S[t] >= k > S[t+1]; unique t ----
    if (tid < NCH) {
        const int SA  = sc_cnt[tid];
        const int SAn = (tid + 1 < NCH) ? sc_cnt[tid + 1] : 0;
        if (SA >= k && SAn < k) {
            s_t   = tid;
            s_acc = SAn;                                       // count in bins > chunk
            s_vs  = (tid + 1 < NCH) ? sc_sum[tid + 1] : 0ULL;  // sum in bins > chunk
        }
    }
    __syncthreads();

    // ---- thread 0: walk <=8 bins, compute loss, accumulate ----
    if (tid == 0) {
        const int t = s_t;
        int acc = s_acc;                 // elements strictly above current bin
        unsigned long long vs = s_vs;    // their fixed-point sum
        for (int j = CHW - 1; j >= 0; --j) {
            const int bin = t * CHW + j;
            const unsigned long long h = hist[bin];
            const int c = (int)(h >> 44);
            if (acc + c >= k) {
                const int r = k - acc;   // 1 <= r <= c
                const int m = c;
                const float sum_b  = (float)(h & SUMMASK) * (1.0f / FIXS);
                const float above  = (float)vs * (1.0f / FIXS);
                const float binw   = 1.0f / mul;
                const float bin_lo = lo + (float)bin * binw;
                float topr;
                if (r >= m) {
                    topr = sum_b;        // whole bin selected: EXACT
                } else if (2 * r <= m) {
                    // top-r of m uniforms in [bin_lo, bin_lo+binw): order-stat est.
                    topr = (float)r * (bin_lo + binw)
                         - binw * (float)r * (float)(r + 1) / (2.0f * (float)(m + 1));
                } else {
                    // complement: exact bin sum minus bottom (m-r) estimate
                    const int q2 = m - r;
                    topr = sum_b - ((float)q2 * bin_lo
                         + binw * (float)q2 * (float)(q2 + 1) / (2.0f * (float)(m + 1)));
                }
                float v = (above + topr) / (float)k;
                v = fminf(fmaxf(v, 1e-9f), 1.0f - 1e-7f);
                const float lab  = label[row];
                const float loss = -(lab * logf(v) + (1.0f - lab) * log1pf(-v));
                atomicAdd(out, loss / (float)B);   // device-scope, cross-XCD safe
                break;
            }
            acc += c;
            vs  += (h & SUMMASK);
        }
    }
}

extern "C" void kernel_launch(void* const* d_in, const int* in_sizes, int n_in,
                              void* d_out, int out_size, void* d_ws, size_t ws_size,
                              hipStream_t stream) {
    const float* scores = (const float*)d_in[0];
    const float* label  = (const float*)d_in[1];
    const int*   seqlen = (const int*)d_in[2];
    float* out = (float*)d_out;

    const int B = in_sizes[1];
    const int T = in_sizes[0] / B;

    // d_out re-poisoned (0xAA) before every timed launch: zero via kernel
    // (no runtime API calls inside kernel_launch -> graph-capture safe).
    zero_out_kernel<<<1, 1, 0, stream>>>(out);
    topk_bce_kernel<<<B, BLK, 0, stream>>>(scores, label, seqlen, out, T, B);
}